// Round 5
// baseline (227.587 us; speedup 1.0000x reference)
//
#include <hip/hip_runtime.h>
#include <hip/hip_bf16.h>

typedef __attribute__((ext_vector_type(8))) short short8;
typedef __attribute__((ext_vector_type(4))) float float4v;
typedef __attribute__((ext_vector_type(16))) float float16v;
typedef unsigned short u16;
typedef unsigned long long ull;

#define KD 1024

__device__ __forceinline__ u16 f2b(float f) {
    __hip_bfloat16 h = __float2bfloat16(f);
    return __builtin_bit_cast(u16, h);
}
__device__ __forceinline__ float b2f(u16 u) {
    unsigned x = ((unsigned)u) << 16;
    return __builtin_bit_cast(float, x);
}
__device__ __forceinline__ float lg_gamma(int h) {
    float gamma = 1.0f - exp2f(-5.0f - 0.5f * (float)h);
    return log2f(gamma);
}

// async global->LDS, 16B per lane; LDS dest is wave-uniform base + lane*16
__device__ __forceinline__ void async_cp16(const u16* g, u16* l) {
    __builtin_amdgcn_global_load_lds(
        (const __attribute__((address_space(1))) void*)g,
        (__attribute__((address_space(3))) void*)l,
        16, 0, 0);
}

// ---------------- fused fp32 -> bf16 converts (x, Wq*0.125, Wk, Wv, Wo) ----------------
__global__ __launch_bounds__(256)
void cvt_all(const float* __restrict__ x, const float* __restrict__ wq,
             const float* __restrict__ wk, const float* __restrict__ wv,
             const float* __restrict__ wo,
             u16* __restrict__ xb, u16* __restrict__ wqkvb, u16* __restrict__ wob)
{
    int bid = blockIdx.x;
    const float* src; u16* dst; long off; float sc = 1.0f;
    if (bid < 4096)      { src = x;  dst = xb;              off = (long)bid * 1024; }
    else if (bid < 5120) { src = wq; dst = wqkvb;           off = (long)(bid - 4096) * 1024; sc = 0.125f; }
    else if (bid < 6144) { src = wk; dst = wqkvb + 1048576; off = (long)(bid - 5120) * 1024; }
    else if (bid < 7168) { src = wv; dst = wqkvb + 2097152; off = (long)(bid - 6144) * 1024; }
    else                 { src = wo; dst = wob;             off = (long)(bid - 7168) * 1024; }
    long i = off + threadIdx.x * 4;
    float4 v = *(const float4*)(src + i);
    ushort4 u;
    u.x = f2b(v.x * sc); u.y = f2b(v.y * sc); u.z = f2b(v.z * sc); u.w = f2b(v.w * sc);
    *(ushort4*)(dst + i) = u;
}

// ---------------- NT GEMM: C[m,n] = sum_k A[m,k]*B[n,k], bf16 32x32x16 MFMA ----------
// Hybrid operand feed: A staged via global_load_lds (XOR-swizzled), B-fragments
// loaded global->VGPR directly (L1/L2-served; halves LDS-read instruction count).
// MODE 0: tile 128x128; QKV epilogue: Q,K direct [t][d]; Kt,Vt via LDS transpose.
// MODE 1: tile 64x128; fp32 store to out[m*1024+n], write-combined order.
template<int MODE>
__global__ __launch_bounds__(256)
void gemm_nt(const u16* __restrict__ A, const u16* __restrict__ Bw,
             u16* __restrict__ oQ, u16* __restrict__ oK,
             u16* __restrict__ oKt, u16* __restrict__ oVt,
             float* __restrict__ of)
{
    constexpr int TM = (MODE == 0) ? 128 : 64;
    constexpr int MI = (MODE == 0) ? 2 : 1;     // 32-row tiles per wave (m-dim)
    // MODE0 needs 32KB for the transpose epilogue scratch; A-tile itself is 16KB.
    __shared__ __attribute__((aligned(16))) u16 Sh[(MODE == 0) ? 16384 : 4096];
    u16* As = Sh;
    const int tid = threadIdx.x;
    const int lane = tid & 63;
    const int wv = tid >> 6;
    const int wm = wv >> 1, wn = wv & 1;
    const int row32 = lane & 31, khalf = lane >> 5;
    const int lrow = lane >> 3, lseg = lane & 7;   // staging: 8 rows x 8 segs per instr
    // XCD-aware grid swizzle: lin%8 ~ XCD; give each XCD a contiguous m-slab.
    const int lin = blockIdx.x + gridDim.x * blockIdx.y;
    const int xcd = lin & 7, idx = lin >> 3;
    int m_tile, n_tile;
    if (MODE == 0) { m_tile = (idx & 3) + 4 * xcd; n_tile = idx >> 2; }   // 32 m, 24 n
    else           { m_tile = (idx & 7) + 8 * xcd; n_tile = idx >> 3; }   // 64 m, 8 n
    const int m0 = m_tile * TM, n0 = n_tile * 128;

    float16v acc[MI][2];
#pragma unroll
    for (int i = 0; i < MI; i++)
#pragma unroll
        for (int j = 0; j < 2; j++)
#pragma unroll
            for (int r = 0; r < 16; r++) acc[i][j][r] = 0.f;

    const int scol = (lseg ^ lrow) << 3;           // swizzled global column (elements)
    // B-fragment base: this lane's row + k-half
    const u16* bp = Bw + (size_t)(n0 + wn * 64 + row32) * KD + khalf * 8;

    for (int kt = 0; kt < KD; kt += 64) {
        __syncthreads();
#pragma unroll
        for (int i = 0; i < TM / 32; i++) {
            int r = wv * (TM / 4) + i * 8;
            async_cp16(A + (size_t)(m0 + r + lrow) * KD + kt + scol, &As[r * 64]);
        }
        // B fragments for this K-tile, direct global->VGPR (no LDS round-trip)
        short8 bgl[4][2];
#pragma unroll
        for (int ks = 0; ks < 4; ks++)
#pragma unroll
            for (int j = 0; j < 2; j++)
                bgl[ks][j] = *(const short8*)(bp + (size_t)j * 32 * KD + kt + ks * 16);
        __syncthreads();
#pragma unroll
        for (int ks = 0; ks < 4; ks++) {
            short8 af[MI];
#pragma unroll
            for (int i = 0; i < MI; i++) {
                int row = wm * (MI * 32) + i * 32 + row32;
                af[i] = *(const short8*)(&As[row * 64 + (((ks * 2 + khalf) ^ (row & 7)) << 3)]);
            }
#pragma unroll
            for (int i = 0; i < MI; i++)
#pragma unroll
                for (int j = 0; j < 2; j++)
                    acc[i][j] = __builtin_amdgcn_mfma_f32_32x32x16_bf16(af[i], bgl[ks][j], acc[i][j], 0, 0, 0);
        }
    }

    if (MODE == 0) {
        const int wsel = n0 >> 10;   // block-uniform: 0=Q, 1=K, 2=V
        if (wsel <= 1) {
            u16* dst = (wsel == 0) ? oQ : oK;
#pragma unroll
            for (int i = 0; i < 2; i++)
#pragma unroll
                for (int j = 0; j < 2; j++) {
                    int gn = n0 + wn * 64 + j * 32 + row32;
                    int dd = gn & 63, hh = (gn >> 6) & 15;
#pragma unroll
                    for (int reg = 0; reg < 16; reg++) {
                        int m = m0 + wm * 64 + i * 32 + (reg & 3) + 8 * (reg >> 2) + 4 * khalf;
                        int b = m >> 11, t = m & 2047;
                        dst[(size_t)(b * 16 + hh) * 131072 + t * 64 + dd] = f2b(acc[i][j][reg]);
                    }
                }
        }
        if (wsel >= 1) {
            // transposed outputs via LDS (reuse scratch): wave tile 64n x 64m
            __syncthreads();
            u16* Tl = Sh + wv * 4096;  // 64 rows(n_loc) x 64 cols(m_loc), 16B-seg XOR swizzle
#pragma unroll
            for (int i = 0; i < 2; i++)
#pragma unroll
                for (int j = 0; j < 2; j++) {
                    int n_loc = j * 32 + row32;
#pragma unroll
                    for (int g = 0; g < 4; g++) {
                        int m4 = i * 32 + 8 * g + 4 * khalf;
                        ull pk = (ull)f2b(acc[i][j][4 * g]) | ((ull)f2b(acc[i][j][4 * g + 1]) << 16) |
                                 ((ull)f2b(acc[i][j][4 * g + 2]) << 32) | ((ull)f2b(acc[i][j][4 * g + 3]) << 48);
                        *(ull*)(&Tl[n_loc * 64 + (((m4 >> 3) ^ (n_loc & 7)) << 3) + (m4 & 7)]) = pk;
                    }
                }
            __syncthreads();
            int gnb = n0 + wn * 64;
            int hh = (gnb >> 6) & 15;
            int mb = m0 + wm * 64;
            int bh = (mb >> 11) * 16 + hh;
            int t0 = mb & 2047;
            u16* dstT = (wsel == 1) ? oKt : oVt;
            int rr = lane >> 3, ss = lane & 7;
#pragma unroll
            for (int g = 0; g < 8; g++) {
                int row = 8 * g + rr;  // dd
                short8 v = *(const short8*)(&Tl[row * 64 + ((ss ^ rr) << 3)]);
                *(short8*)(&dstT[(size_t)bh * 131072 + (size_t)row * 2048 + t0 + ss * 8]) = v;
            }
        }
    } else {
        // write-combining order: same m row's two 128B pieces in adjacent stores
        int gn0 = n0 + wn * 64 + row32;
#pragma unroll
        for (int g = 0; g < 4; g++)
#pragma unroll
            for (int rr = 0; rr < 4; rr++) {
                int reg = 4 * g + rr;
                int m = m0 + wm * 32 + 8 * g + 4 * khalf + rr;
                of[(size_t)m * 1024 + gn0] = acc[0][0][reg];
                of[(size_t)m * 1024 + gn0 + 32] = acc[0][1][reg];
            }
    }
}

// ---------------- Pass A: per-chunk summary U^T[d2][d1] = sum_b g^(63-b) V[b,d2] K[b,d1] ----
__global__ __launch_bounds__(256)
void chunk_state(const u16* __restrict__ Kt, const u16* __restrict__ Vt,
                 u16* __restrict__ U)
{
    const int c = blockIdx.x, bh = blockIdx.y, h = bh & 15;
    const int tid = threadIdx.x, lane = tid & 63, w = tid >> 6;
    const int row16 = lane & 15, quad = lane >> 4;
    const float lg = lg_gamma(h);
    const size_t base = (size_t)bh * 131072;

    float4v acc[4];
    float4v zero4 = {0.f, 0.f, 0.f, 0.f};
#pragma unroll
    for (int tn = 0; tn < 4; tn++) acc[tn] = zero4;

#pragma unroll
    for (int kb = 0; kb < 2; kb++) {
        short8 a = *(const short8*)(Vt + base + (size_t)(16 * w + row16) * 2048 + c * 64 + kb * 32 + quad * 8);
        short8 as;
        int e0 = 63 - (kb * 32 + quad * 8);
#pragma unroll
        for (int jj = 0; jj < 8; jj++) {
            float v = b2f((u16)a[jj]) * exp2f(lg * (float)(e0 - jj));
            as[jj] = (short)f2b(v);
        }
#pragma unroll
        for (int tn = 0; tn < 4; tn++) {
            short8 bfr = *(const short8*)(Kt + base + (size_t)(16 * tn + row16) * 2048 + c * 64 + kb * 32 + quad * 8);
            acc[tn] = __builtin_amdgcn_mfma_f32_16x16x32_bf16(as, bfr, acc[tn], 0, 0, 0);
        }
    }
    u16* up = U + ((size_t)bh * 32 + c) * 4096;
#pragma unroll
    for (int tn = 0; tn < 4; tn++)
#pragma unroll
        for (int r = 0; r < 4; r++)
            up[(16 * w + quad * 4 + r) * 64 + 16 * tn + row16] = f2b(acc[tn][r]);
}

// ---------------- Pass B: parallel over (bh, element); sequential only over 32 chunks ----
__global__ __launch_bounds__(256)
void state_scan(const u16* __restrict__ U, u16* __restrict__ St)
{
    const int bh = blockIdx.y;
    const int e = blockIdx.x * 256 + threadIdx.x;  // 0..4095
    const float g64 = exp2f(lg_gamma(bh & 15) * 64.0f);
    float s = 0.f;
    St[(size_t)bh * 131072 + e] = 0;
    for (int c = 1; c < 32; c++) {
        s = g64 * s + b2f(U[((size_t)bh * 32 + (c - 1)) * 4096 + e]);
        St[((size_t)bh * 32 + c) * 4096 + e] = f2b(s);
    }
}

// ---------------- Pass C: per-chunk output = intra + inter, fused GN partial sums ----
__global__ __launch_bounds__(256)
void retention_chunk(const u16* __restrict__ Q, const u16* __restrict__ Kb,
                     const u16* __restrict__ Vt, const u16* __restrict__ St,
                     float* __restrict__ Y, float* __restrict__ stats)
{
    __shared__ __attribute__((aligned(16))) u16 Pl[4][16 * 72];
    __shared__ float red[8];
    const int c = blockIdx.x, bh = blockIdx.y, h = bh & 15;
    const int tid = threadIdx.x, lane = tid & 63, w = tid >> 6;
    const int row16 = lane & 15, quad = lane >> 4;
    const float lg = lg_gamma(h);
    const size_t base = (size_t)bh * 131072;
    float4v zero4 = {0.f, 0.f, 0.f, 0.f};

    short8 qf[2];
#pragma unroll
    for (int kb = 0; kb < 2; kb++)
        qf[kb] = *(const short8*)(Q + base + (size_t)(c * 64 + 16 * w + row16) * 64 + kb * 32 + quad * 8);

    // Phase 1: P = (Q*0.125) K^T   (rows: this wave's 16, cols: 64)
    float4v accp[4];
#pragma unroll
    for (int tn = 0; tn < 4; tn++) accp[tn] = zero4;
#pragma unroll
    for (int tn = 0; tn < 4; tn++)
#pragma unroll
        for (int kb = 0; kb < 2; kb++) {
            short8 kf = *(const short8*)(Kb + base + (size_t)(c * 64 + 16 * tn + row16) * 64 + kb * 32 + quad * 8);
            accp[tn] = __builtin_amdgcn_mfma_f32_16x16x32_bf16(qf[kb], kf, accp[tn], 0, 0, 0);
        }
    // decay mask, write to LDS in A-layout-friendly row-major [16][72]
#pragma unroll
    for (int tn = 0; tn < 4; tn++)
#pragma unroll
        for (int r = 0; r < 4; r++) {
            int a_loc = 16 * w + quad * 4 + r;
            int b_loc = 16 * tn + row16;
            int d = a_loc - b_loc;
            float v = (d >= 0) ? accp[tn][r] * exp2f(lg * (float)d) : 0.f;
            Pl[w][(quad * 4 + r) * 72 + b_loc] = f2b(v);
        }
    __syncthreads();

    short8 pf[2];
#pragma unroll
    for (int kb = 0; kb < 2; kb++)
        pf[kb] = *(const short8*)(&Pl[w][row16 * 72 + kb * 32 + quad * 8]);

    float4v acco[4], acci[4];
#pragma unroll
    for (int tn = 0; tn < 4; tn++) { acco[tn] = zero4; acci[tn] = zero4; }
#pragma unroll
    for (int tn = 0; tn < 4; tn++)
#pragma unroll
        for (int kb = 0; kb < 2; kb++) {
            short8 vf = *(const short8*)(Vt + base + (size_t)(16 * tn + row16) * 2048 + c * 64 + kb * 32 + quad * 8);
            acco[tn] = __builtin_amdgcn_mfma_f32_16x16x32_bf16(pf[kb], vf, acco[tn], 0, 0, 0);
            short8 sf = *(const short8*)(St + ((size_t)bh * 32 + c) * 4096 + (16 * tn + row16) * 64 + kb * 32 + quad * 8);
            acci[tn] = __builtin_amdgcn_mfma_f32_16x16x32_bf16(qf[kb], sf, acci[tn], 0, 0, 0);
        }

    float s = 0.f, s2 = 0.f;
#pragma unroll
    for (int tn = 0; tn < 4; tn++)
#pragma unroll
        for (int r = 0; r < 4; r++) {
            int a_loc = 16 * w + quad * 4 + r;
            float gi = exp2f(lg * (float)(a_loc + 1));
            int t = c * 64 + a_loc, d2 = 16 * tn + row16;
            float yv = acco[tn][r] + gi * acci[tn][r];
            Y[(size_t)bh * 131072 + t * 64 + d2] = yv;
            s += yv;
            s2 += yv * yv;
        }
    // fused GN partial sums: wave reduce -> LDS -> one atomic pair per block
#pragma unroll
    for (int off = 32; off; off >>= 1) {
        s += __shfl_down(s, off, 64);
        s2 += __shfl_down(s2, off, 64);
    }
    if (lane == 0) { red[w] = s; red[4 + w] = s2; }
    __syncthreads();
    if (tid == 0) {
        atomicAdd(&stats[2 * bh], red[0] + red[1] + red[2] + red[3]);
        atomicAdd(&stats[2 * bh + 1], red[4] + red[5] + red[6] + red[7]);
    }
}

// ---------------- apply GN (mu/rsig from raw sums), emit Z bf16 in [b][t][c] ----------------
__global__ __launch_bounds__(256)
void gn_apply(const float* __restrict__ Y, const float* __restrict__ stats,
              const float* __restrict__ gnw, const float* __restrict__ gnb,
              u16* __restrict__ Z)
{
    int i4 = (blockIdx.x * 256 + threadIdx.x) * 4;
    int b = i4 >> 21, t = (i4 >> 10) & 2047, cc = i4 & 1023;
    int hh = cc >> 6, dd = cc & 63, bh = b * 16 + hh;
    float4 v = *(const float4*)(Y + (size_t)bh * 131072 + t * 64 + dd);
    float S = stats[2 * bh], S2 = stats[2 * bh + 1];
    float mu = S * (1.0f / 131072.f);
    float var = S2 * (1.0f / 131072.f) - mu * mu;
    float rsg = rsqrtf(var + 1e-5f);
    float4 wv = *(const float4*)(gnw + cc);
    float4 bv = *(const float4*)(gnb + cc);
    ushort4 o;
    o.x = f2b((v.x - mu) * rsg * wv.x + bv.x);
    o.y = f2b((v.y - mu) * rsg * wv.y + bv.y);
    o.z = f2b((v.z - mu) * rsg * wv.z + bv.z);
    o.w = f2b((v.w - mu) * rsg * wv.w + bv.w);
    *(ushort4*)(Z + i4) = o;
}

extern "C" void kernel_launch(void* const* d_in, const int* in_sizes, int n_in,
                              void* d_out, int out_size, void* d_ws, size_t ws_size,
                              hipStream_t stream) {
    const float* x   = (const float*)d_in[0];
    const float* Wq  = (const float*)d_in[1];
    const float* Wk  = (const float*)d_in[2];
    const float* Wv  = (const float*)d_in[3];
    const float* Wo  = (const float*)d_in[4];
    const float* gnw = (const float*)d_in[5];
    const float* gnb = (const float*)d_in[6];
    float* out = (float*)d_out;
    char* ws = (char*)d_ws;

    u16*  xb    = (u16*)(ws + 0);           // 8 MB
    u16*  wqkvb = (u16*)(ws + 8388608);     // 6 MB  [3][1024][1024] (Wq pre-scaled 0.125)
    u16*  wob   = (u16*)(ws + 14680064);    // 2 MB
    u16*  Qs    = (u16*)(ws + 16777216);    // 8 MB  [bh][t][d]
    u16*  Kb    = (u16*)(ws + 25165824);    // 8 MB  [bh][t][d]
    u16*  Kt    = (u16*)(ws + 33554432);    // 8 MB  [bh][d][t]
    u16*  Vt    = (u16*)(ws + 41943040);    // 8 MB  [bh][d][t]
    u16*  U     = (u16*)(ws + 50331648);    // 8 MB  [bh][c][64][64] (U^T bf16)
    u16*  St    = (u16*)(ws + 67108864);    // 8 MB  [bh][c][64][64] (S^T, state entering c)
    float* Y    = (float*)(ws + 75497472);  // 16 MB [bh][t][d]
    u16*  Zb    = (u16*)(ws + 92274688);    // 8 MB  [b][t][c]
    float* stats= (float*)(ws + 100663296); // 256 B raw sums (S, S2) per bh

    hipMemsetAsync(stats, 0, 64 * sizeof(float), stream);

    cvt_all<<<8192, 256, 0, stream>>>(x, Wq, Wk, Wv, Wo, xb, wqkvb, wob);

    gemm_nt<0><<<dim3(24, 32), 256, 0, stream>>>(xb, wqkvb, Qs, Kb, Kt, Vt, nullptr);

    chunk_state<<<dim3(32, 32), 256, 0, stream>>>(Kt, Vt, U);
    state_scan<<<dim3(16, 32), 256, 0, stream>>>(U, St);
    retention_chunk<<<dim3(32, 32), 256, 0, stream>>>(Qs, Kb, Vt, St, Y, stats);

    gn_apply<<<4096, 256, 0, stream>>>(Y, stats, gnw, gnb, Zb);

    gemm_nt<1><<<dim3(8, 64), 256, 0, stream>>>(Zb, wob, nullptr, nullptr, nullptr, nullptr, out);
}

// Round 6
// 185.128 us; speedup vs baseline: 1.2294x; 1.2294x over previous
//
#include <hip/hip_runtime.h>
#include <hip/hip_bf16.h>

typedef __attribute__((ext_vector_type(8))) short short8;
typedef __attribute__((ext_vector_type(4))) float float4v;
typedef __attribute__((ext_vector_type(16))) float float16v;
typedef unsigned short u16;
typedef unsigned long long ull;

#define KD 1024

__device__ __forceinline__ u16 f2b(float f) {
    __hip_bfloat16 h = __float2bfloat16(f);
    return __builtin_bit_cast(u16, h);
}
__device__ __forceinline__ float b2f(u16 u) {
    unsigned x = ((unsigned)u) << 16;
    return __builtin_bit_cast(float, x);
}
__device__ __forceinline__ float lg_gamma(int h) {
    float gamma = 1.0f - exp2f(-5.0f - 0.5f * (float)h);
    return log2f(gamma);
}

// async global->LDS, 16B per lane; LDS dest is wave-uniform base + lane*16
__device__ __forceinline__ void async_cp16(const u16* g, u16* l) {
    __builtin_amdgcn_global_load_lds(
        (const __attribute__((address_space(1))) void*)g,
        (__attribute__((address_space(3))) void*)l,
        16, 0, 0);
}

// ---------------- fused converts ----------------
// x -> xb row-major bf16.
// Weights -> MFMA-fragment-packed bf16: offset = panel*32768 + kg*512 + kh*256 + row*8 + off
//   (panel = n>>5, row = n&31, kg = k>>4, kh = (k>>3)&1, off = k&7)
// so a wave B-fragment load is base + lane*16B (coalesced 1KB).
__global__ __launch_bounds__(256)
void cvt_all(const float* __restrict__ x, const float* __restrict__ wq,
             const float* __restrict__ wk, const float* __restrict__ wv,
             const float* __restrict__ wo,
             u16* __restrict__ xb, u16* __restrict__ wqkvb, u16* __restrict__ wob)
{
    int bid = blockIdx.x;
    if (bid < 4096) {
        long i = (long)bid * 1024 + threadIdx.x * 4;
        float4 v = *(const float4*)(x + i);
        ushort4 u;
        u.x = f2b(v.x); u.y = f2b(v.y); u.z = f2b(v.z); u.w = f2b(v.w);
        *(ushort4*)(xb + i) = u;
    } else {
        int wbid = bid - 4096;          // 0..4095
        int mtx = wbid >> 10;           // 0=wq 1=wk 2=wv 3=wo
        int n = wbid & 1023;
        const float* src = (mtx == 0) ? wq : (mtx == 1) ? wk : (mtx == 2) ? wv : wo;
        u16* dst = (mtx == 3) ? wob : (wqkvb + (size_t)mtx * 1048576);
        float sc = (mtx == 0) ? 0.125f : 1.0f;
        int k0 = threadIdx.x * 4;
        float4 v = *(const float4*)(src + (size_t)n * 1024 + k0);
        int panel = n >> 5, row = n & 31, kg = k0 >> 4, kh = (k0 >> 3) & 1, off = k0 & 7;
        size_t o = (size_t)panel * 32768 + (size_t)kg * 512 + kh * 256 + row * 8 + off;
        ushort4 u;
        u.x = f2b(v.x * sc); u.y = f2b(v.y * sc); u.z = f2b(v.z * sc); u.w = f2b(v.w * sc);
        *(ushort4*)(dst + o) = u;
    }
}

// ---------------- NT GEMM: C[m,n] = sum_k A[m,k]*B[n,k], bf16 32x32x16 MFMA ----------
// A staged via global_load_lds (XOR-swizzled LDS); B read as pre-packed fragments
// directly global->VGPR (coalesced 1KB per instr, L1/L2-served). LDS traffic halved.
// MODE 0: tile 128x128; QKV epilogue: Q,K direct [t][d]; Kt,Vt via LDS transpose.
// MODE 1: tile 64x128; fp32 store to out[m*1024+n].
template<int MODE>
__global__ __launch_bounds__(256)
void gemm_nt(const u16* __restrict__ A, const u16* __restrict__ Bpk,
             u16* __restrict__ oQ, u16* __restrict__ oK,
             u16* __restrict__ oKt, u16* __restrict__ oVt,
             float* __restrict__ of)
{
    constexpr int TM = (MODE == 0) ? 128 : 64;
    constexpr int MI = (MODE == 0) ? 2 : 1;     // 32-row tiles per wave (m-dim)
    // MODE0: A-tile 16KB + transpose scratch reuse => 32KB total. MODE1: 8KB.
    __shared__ __attribute__((aligned(16))) u16 Sh[(MODE == 0) ? 16384 : 4096];
    u16* As = Sh;
    const int tid = threadIdx.x;
    const int lane = tid & 63;
    const int wv = tid >> 6;
    const int wm = wv >> 1, wn = wv & 1;
    const int row32 = lane & 31, khalf = lane >> 5;
    const int lrow = lane >> 3, lseg = lane & 7;   // staging: 8 rows x 8 segs per instr
    // XCD-aware grid swizzle: lin%8 ~ XCD; give each XCD a contiguous m-slab.
    const int lin = blockIdx.x + gridDim.x * blockIdx.y;
    const int xcd = lin & 7, idx = lin >> 3;
    int m_tile, n_tile;
    if (MODE == 0) { m_tile = (idx & 3) + 4 * xcd; n_tile = idx >> 2; }   // 32 m, 24 n
    else           { m_tile = (idx & 7) + 8 * xcd; n_tile = idx >> 3; }   // 64 m, 8 n
    const int m0 = m_tile * TM, n0 = n_tile * 128;

    float16v acc[MI][2];
#pragma unroll
    for (int i = 0; i < MI; i++)
#pragma unroll
        for (int j = 0; j < 2; j++)
#pragma unroll
            for (int r = 0; r < 16; r++) acc[i][j][r] = 0.f;

    const int scol = (lseg ^ lrow) << 3;           // swizzled global column (elements)
    // packed-B pointer: panel = n0/32 + wn*2 (+j), lane offset = lane*8 elems
    const u16* bp = Bpk + (size_t)((n0 >> 5) + wn * 2) * 32768 + (size_t)lane * 8;

    for (int kt = 0; kt < KD; kt += 64) {
        __syncthreads();
#pragma unroll
        for (int i = 0; i < TM / 32; i++) {
            int r = wv * (TM / 4) + i * 8;
            async_cp16(A + (size_t)(m0 + r + lrow) * KD + kt + scol, &As[r * 64]);
        }
        // B fragments for this K-tile: coalesced packed global->VGPR
        short8 bgl[4][2];
#pragma unroll
        for (int ks = 0; ks < 4; ks++)
#pragma unroll
            for (int j = 0; j < 2; j++)
                bgl[ks][j] = *(const short8*)(bp + (size_t)j * 32768 + ((kt >> 4) + ks) * 512);
        __syncthreads();
#pragma unroll
        for (int ks = 0; ks < 4; ks++) {
            short8 af[MI];
#pragma unroll
            for (int i = 0; i < MI; i++) {
                int row = wm * (MI * 32) + i * 32 + row32;
                af[i] = *(const short8*)(&As[row * 64 + (((ks * 2 + khalf) ^ (row & 7)) << 3)]);
            }
#pragma unroll
            for (int i = 0; i < MI; i++)
#pragma unroll
                for (int j = 0; j < 2; j++)
                    acc[i][j] = __builtin_amdgcn_mfma_f32_32x32x16_bf16(af[i], bgl[ks][j], acc[i][j], 0, 0, 0);
        }
    }

    if (MODE == 0) {
        const int wsel = n0 >> 10;   // block-uniform: 0=Q, 1=K, 2=V
        if (wsel <= 1) {
            u16* dst = (wsel == 0) ? oQ : oK;
#pragma unroll
            for (int i = 0; i < 2; i++)
#pragma unroll
                for (int j = 0; j < 2; j++) {
                    int gn = n0 + wn * 64 + j * 32 + row32;
                    int dd = gn & 63, hh = (gn >> 6) & 15;
#pragma unroll
                    for (int reg = 0; reg < 16; reg++) {
                        int m = m0 + wm * 64 + i * 32 + (reg & 3) + 8 * (reg >> 2) + 4 * khalf;
                        int b = m >> 11, t = m & 2047;
                        dst[(size_t)(b * 16 + hh) * 131072 + t * 64 + dd] = f2b(acc[i][j][reg]);
                    }
                }
        }
        if (wsel >= 1) {
            // transposed outputs via LDS (reuse scratch): wave tile 64n x 64m
            __syncthreads();
            u16* Tl = Sh + wv * 4096;  // 64 rows(n_loc) x 64 cols(m_loc), 16B-seg XOR swizzle
#pragma unroll
            for (int i = 0; i < 2; i++)
#pragma unroll
                for (int j = 0; j < 2; j++) {
                    int n_loc = j * 32 + row32;
#pragma unroll
                    for (int g = 0; g < 4; g++) {
                        int m4 = i * 32 + 8 * g + 4 * khalf;
                        ull pk = (ull)f2b(acc[i][j][4 * g]) | ((ull)f2b(acc[i][j][4 * g + 1]) << 16) |
                                 ((ull)f2b(acc[i][j][4 * g + 2]) << 32) | ((ull)f2b(acc[i][j][4 * g + 3]) << 48);
                        *(ull*)(&Tl[n_loc * 64 + (((m4 >> 3) ^ (n_loc & 7)) << 3) + (m4 & 7)]) = pk;
                    }
                }
            __syncthreads();
            int gnb = n0 + wn * 64;
            int hh = (gnb >> 6) & 15;
            int mb = m0 + wm * 64;
            int bh = (mb >> 11) * 16 + hh;
            int t0 = mb & 2047;
            u16* dstT = (wsel == 1) ? oKt : oVt;
            int rr = lane >> 3, ss = lane & 7;
#pragma unroll
            for (int g = 0; g < 8; g++) {
                int row = 8 * g + rr;  // dd
                short8 v = *(const short8*)(&Tl[row * 64 + ((ss ^ rr) << 3)]);
                *(short8*)(&dstT[(size_t)bh * 131072 + (size_t)row * 2048 + t0 + ss * 8]) = v;
            }
        }
    } else {
        // write-combining order: same m row's two 128B pieces in adjacent stores
        int gn0 = n0 + wn * 64 + row32;
#pragma unroll
        for (int g = 0; g < 4; g++)
#pragma unroll
            for (int rr = 0; rr < 4; rr++) {
                int reg = 4 * g + rr;
                int m = m0 + wm * 32 + 8 * g + 4 * khalf + rr;
                of[(size_t)m * 1024 + gn0] = acc[0][0][reg];
                of[(size_t)m * 1024 + gn0 + 32] = acc[0][1][reg];
            }
    }
}

// ---------------- Pass A: per-chunk summary U^T[d2][d1] = sum_b g^(63-b) V[b,d2] K[b,d1] ----
__global__ __launch_bounds__(256)
void chunk_state(const u16* __restrict__ Kt, const u16* __restrict__ Vt,
                 u16* __restrict__ U)
{
    const int c = blockIdx.x, bh = blockIdx.y, h = bh & 15;
    const int tid = threadIdx.x, lane = tid & 63, w = tid >> 6;
    const int row16 = lane & 15, quad = lane >> 4;
    const float lg = lg_gamma(h);
    const size_t base = (size_t)bh * 131072;

    float4v acc[4];
    float4v zero4 = {0.f, 0.f, 0.f, 0.f};
#pragma unroll
    for (int tn = 0; tn < 4; tn++) acc[tn] = zero4;

#pragma unroll
    for (int kb = 0; kb < 2; kb++) {
        short8 a = *(const short8*)(Vt + base + (size_t)(16 * w + row16) * 2048 + c * 64 + kb * 32 + quad * 8);
        short8 as;
        int e0 = 63 - (kb * 32 + quad * 8);
#pragma unroll
        for (int jj = 0; jj < 8; jj++) {
            float v = b2f((u16)a[jj]) * exp2f(lg * (float)(e0 - jj));
            as[jj] = (short)f2b(v);
        }
#pragma unroll
        for (int tn = 0; tn < 4; tn++) {
            short8 bfr = *(const short8*)(Kt + base + (size_t)(16 * tn + row16) * 2048 + c * 64 + kb * 32 + quad * 8);
            acc[tn] = __builtin_amdgcn_mfma_f32_16x16x32_bf16(as, bfr, acc[tn], 0, 0, 0);
        }
    }
    u16* up = U + ((size_t)bh * 32 + c) * 4096;
#pragma unroll
    for (int tn = 0; tn < 4; tn++)
#pragma unroll
        for (int r = 0; r < 4; r++)
            up[(16 * w + quad * 4 + r) * 64 + 16 * tn + row16] = f2b(acc[tn][r]);
}

// ---------------- Pass B: parallel over (bh, element); sequential only over 32 chunks ----
__global__ __launch_bounds__(256)
void state_scan(const u16* __restrict__ U, u16* __restrict__ St)
{
    const int bh = blockIdx.y;
    const int e = blockIdx.x * 256 + threadIdx.x;  // 0..4095
    const float g64 = exp2f(lg_gamma(bh & 15) * 64.0f);
    float s = 0.f;
    St[(size_t)bh * 131072 + e] = 0;
    for (int c = 1; c < 32; c++) {
        s = g64 * s + b2f(U[((size_t)bh * 32 + (c - 1)) * 4096 + e]);
        St[((size_t)bh * 32 + c) * 4096 + e] = f2b(s);
    }
}

// ---------------- Pass C: per-chunk output = intra + inter, fused GN partial sums ----
__global__ __launch_bounds__(256)
void retention_chunk(const u16* __restrict__ Q, const u16* __restrict__ Kb,
                     const u16* __restrict__ Vt, const u16* __restrict__ St,
                     float* __restrict__ Y, float* __restrict__ stats)
{
    __shared__ __attribute__((aligned(16))) u16 Pl[4][16 * 72];
    __shared__ float red[8];
    const int c = blockIdx.x, bh = blockIdx.y, h = bh & 15;
    const int tid = threadIdx.x, lane = tid & 63, w = tid >> 6;
    const int row16 = lane & 15, quad = lane >> 4;
    const float lg = lg_gamma(h);
    const size_t base = (size_t)bh * 131072;
    float4v zero4 = {0.f, 0.f, 0.f, 0.f};

    short8 qf[2];
#pragma unroll
    for (int kb = 0; kb < 2; kb++)
        qf[kb] = *(const short8*)(Q + base + (size_t)(c * 64 + 16 * w + row16) * 64 + kb * 32 + quad * 8);

    // Phase 1: P = (Q*0.125) K^T   (rows: this wave's 16, cols: 64)
    float4v accp[4];
#pragma unroll
    for (int tn = 0; tn < 4; tn++) accp[tn] = zero4;
#pragma unroll
    for (int tn = 0; tn < 4; tn++)
#pragma unroll
        for (int kb = 0; kb < 2; kb++) {
            short8 kf = *(const short8*)(Kb + base + (size_t)(c * 64 + 16 * tn + row16) * 64 + kb * 32 + quad * 8);
            accp[tn] = __builtin_amdgcn_mfma_f32_16x16x32_bf16(qf[kb], kf, accp[tn], 0, 0, 0);
        }
    // decay mask, write to LDS in A-layout-friendly row-major [16][72]
#pragma unroll
    for (int tn = 0; tn < 4; tn++)
#pragma unroll
        for (int r = 0; r < 4; r++) {
            int a_loc = 16 * w + quad * 4 + r;
            int b_loc = 16 * tn + row16;
            int d = a_loc - b_loc;
            float v = (d >= 0) ? accp[tn][r] * exp2f(lg * (float)d) : 0.f;
            Pl[w][(quad * 4 + r) * 72 + b_loc] = f2b(v);
        }
    __syncthreads();

    short8 pf[2];
#pragma unroll
    for (int kb = 0; kb < 2; kb++)
        pf[kb] = *(const short8*)(&Pl[w][row16 * 72 + kb * 32 + quad * 8]);

    float4v acco[4], acci[4];
#pragma unroll
    for (int tn = 0; tn < 4; tn++) { acco[tn] = zero4; acci[tn] = zero4; }
#pragma unroll
    for (int tn = 0; tn < 4; tn++)
#pragma unroll
        for (int kb = 0; kb < 2; kb++) {
            short8 vf = *(const short8*)(Vt + base + (size_t)(16 * tn + row16) * 2048 + c * 64 + kb * 32 + quad * 8);
            acco[tn] = __builtin_amdgcn_mfma_f32_16x16x32_bf16(pf[kb], vf, acco[tn], 0, 0, 0);
            short8 sf = *(const short8*)(St + ((size_t)bh * 32 + c) * 4096 + (16 * tn + row16) * 64 + kb * 32 + quad * 8);
            acci[tn] = __builtin_amdgcn_mfma_f32_16x16x32_bf16(qf[kb], sf, acci[tn], 0, 0, 0);
        }

    float s = 0.f, s2 = 0.f;
#pragma unroll
    for (int tn = 0; tn < 4; tn++)
#pragma unroll
        for (int r = 0; r < 4; r++) {
            int a_loc = 16 * w + quad * 4 + r;
            float gi = exp2f(lg * (float)(a_loc + 1));
            int t = c * 64 + a_loc, d2 = 16 * tn + row16;
            float yv = acco[tn][r] + gi * acci[tn][r];
            Y[(size_t)bh * 131072 + t * 64 + d2] = yv;
            s += yv;
            s2 += yv * yv;
        }
    // fused GN partial sums: wave reduce -> LDS -> one atomic pair per block
#pragma unroll
    for (int off = 32; off; off >>= 1) {
        s += __shfl_down(s, off, 64);
        s2 += __shfl_down(s2, off, 64);
    }
    if (lane == 0) { red[w] = s; red[4 + w] = s2; }
    __syncthreads();
    if (tid == 0) {
        atomicAdd(&stats[2 * bh], red[0] + red[1] + red[2] + red[3]);
        atomicAdd(&stats[2 * bh + 1], red[4] + red[5] + red[6] + red[7]);
    }
}

// ---------------- apply GN (mu/rsig from raw sums), emit Z bf16 in [b][t][c] ----------------
__global__ __launch_bounds__(256)
void gn_apply(const float* __restrict__ Y, const float* __restrict__ stats,
              const float* __restrict__ gnw, const float* __restrict__ gnb,
              u16* __restrict__ Z)
{
    int i4 = (blockIdx.x * 256 + threadIdx.x) * 4;
    int b = i4 >> 21, t = (i4 >> 10) & 2047, cc = i4 & 1023;
    int hh = cc >> 6, dd = cc & 63, bh = b * 16 + hh;
    float4 v = *(const float4*)(Y + (size_t)bh * 131072 + t * 64 + dd);
    float S = stats[2 * bh], S2 = stats[2 * bh + 1];
    float mu = S * (1.0f / 131072.f);
    float var = S2 * (1.0f / 131072.f) - mu * mu;
    float rsg = rsqrtf(var + 1e-5f);
    float4 wv = *(const float4*)(gnw + cc);
    float4 bv = *(const float4*)(gnb + cc);
    ushort4 o;
    o.x = f2b((v.x - mu) * rsg * wv.x + bv.x);
    o.y = f2b((v.y - mu) * rsg * wv.y + bv.y);
    o.z = f2b((v.z - mu) * rsg * wv.z + bv.z);
    o.w = f2b((v.w - mu) * rsg * wv.w + bv.w);
    *(ushort4*)(Z + i4) = o;
}

extern "C" void kernel_launch(void* const* d_in, const int* in_sizes, int n_in,
                              void* d_out, int out_size, void* d_ws, size_t ws_size,
                              hipStream_t stream) {
    const float* x   = (const float*)d_in[0];
    const float* Wq  = (const float*)d_in[1];
    const float* Wk  = (const float*)d_in[2];
    const float* Wv  = (const float*)d_in[3];
    const float* Wo  = (const float*)d_in[4];
    const float* gnw = (const float*)d_in[5];
    const float* gnb = (const float*)d_in[6];
    float* out = (float*)d_out;
    char* ws = (char*)d_ws;

    u16*  xb    = (u16*)(ws + 0);           // 8 MB  [b*t][c] row-major
    u16*  wqkvb = (u16*)(ws + 8388608);     // 6 MB  packed fragments (Wq pre-scaled 0.125)
    u16*  wob   = (u16*)(ws + 14680064);    // 2 MB  packed fragments
    u16*  Qs    = (u16*)(ws + 16777216);    // 8 MB  [bh][t][d]
    u16*  Kb    = (u16*)(ws + 25165824);    // 8 MB  [bh][t][d]
    u16*  Kt    = (u16*)(ws + 33554432);    // 8 MB  [bh][d][t]
    u16*  Vt    = (u16*)(ws + 41943040);    // 8 MB  [bh][d][t]
    u16*  U     = (u16*)(ws + 50331648);    // 8 MB  [bh][c][64][64] (U^T bf16)
    u16*  St    = (u16*)(ws + 67108864);    // 8 MB  [bh][c][64][64] (S^T, state entering c)
    float* Y    = (float*)(ws + 75497472);  // 16 MB [bh][t][d]
    u16*  Zb    = (u16*)(ws + 92274688);    // 8 MB  [b][t][c]
    float* stats= (float*)(ws + 100663296); // 256 B raw sums (S, S2) per bh

    hipMemsetAsync(stats, 0, 64 * sizeof(float), stream);

    cvt_all<<<8192, 256, 0, stream>>>(x, Wq, Wk, Wv, Wo, xb, wqkvb, wob);

    gemm_nt<0><<<dim3(24, 32), 256, 0, stream>>>(xb, wqkvb, Qs, Kb, Kt, Vt, nullptr);

    chunk_state<<<dim3(32, 32), 256, 0, stream>>>(Kt, Vt, U);
    state_scan<<<dim3(16, 32), 256, 0, stream>>>(U, St);
    retention_chunk<<<dim3(32, 32), 256, 0, stream>>>(Qs, Kb, Vt, St, Y, stats);

    gn_apply<<<4096, 256, 0, stream>>>(Y, stats, gnw, gnb, Zb);

    gemm_nt<1><<<dim3(8, 64), 256, 0, stream>>>(Zb, wob, nullptr, nullptr, nullptr, nullptr, out);
}